// Round 1
// baseline (1082.860 us; speedup 1.0000x reference)
//
#include <hip/hip_runtime.h>
#include <cstdint>
#include <cmath>

#define NLVL 16

struct Params {
    float    scale[NLVL];
    uint32_t side[NLVL];
    uint32_t offset[NLVL];
    uint32_t hashed[NLVL];
};

__device__ __forceinline__ uint32_t umin32(uint32_t a, uint32_t b) { return a < b ? a : b; }

__global__ __launch_bounds__(256) void grid_encode(
    const float* __restrict__ in,
    const float* __restrict__ emb,
    float* __restrict__ out,
    Params P)
{
    const uint32_t i = blockIdx.x * 256u + threadIdx.x;
    const float x = in[3u * i + 0u];
    const float y = in[3u * i + 1u];
    const float z = in[3u * i + 2u];

    const float2* __restrict__ e2 = (const float2*)emb;
    float* __restrict__ outp = out + (size_t)i * 32u;

    #pragma unroll 1
    for (int l = 0; l < NLVL; ++l) {
        const float    scale  = P.scale[l];
        const uint32_t side   = P.side[l];
        const uint32_t off    = P.offset[l];
        const uint32_t hashed = P.hashed[l];

        // pos = input*scale + 0.5 (mul then add, like the reference)
        float p0 = x * scale + 0.5f;
        float p1 = y * scale + 0.5f;
        float p2 = z * scale + 0.5f;
        float fl0 = floorf(p0), fl1 = floorf(p1), fl2 = floorf(p2);
        float f0 = p0 - fl0, f1 = p1 - fl1, f2 = p2 - fl2;
        uint32_t g0 = (uint32_t)fl0, g1 = (uint32_t)fl1, g2 = (uint32_t)fl2;

        const uint32_t smax = side - 1u;
        uint32_t c0a = umin32(g0, smax),      c0b = umin32(g0 + 1u, smax);
        uint32_t c1a = umin32(g1, smax),      c1b = umin32(g1 + 1u, smax);
        uint32_t c2a = umin32(g2, smax),      c2b = umin32(g2 + 1u, smax);

        uint32_t idx0, idx1, idx2, idx3, idx4, idx5, idx6, idx7;
        if (hashed) {
            const uint32_t h1a = c1a * 2654435761u, h1b = c1b * 2654435761u;
            const uint32_t h2a = c2a * 805459861u,  h2b = c2b * 805459861u;
            // corner id: bit2 -> dim0, bit1 -> dim1, bit0 -> dim2
            idx0 = ((c0a ^ h1a ^ h2a) & 0x7FFFFu) + off;
            idx1 = ((c0a ^ h1a ^ h2b) & 0x7FFFFu) + off;
            idx2 = ((c0a ^ h1b ^ h2a) & 0x7FFFFu) + off;
            idx3 = ((c0a ^ h1b ^ h2b) & 0x7FFFFu) + off;
            idx4 = ((c0b ^ h1a ^ h2a) & 0x7FFFFu) + off;
            idx5 = ((c0b ^ h1a ^ h2b) & 0x7FFFFu) + off;
            idx6 = ((c0b ^ h1b ^ h2a) & 0x7FFFFu) + off;
            idx7 = ((c0b ^ h1b ^ h2b) & 0x7FFFFu) + off;
        } else {
            const uint32_t s2 = side * side;
            const uint32_t b1a = c1a * side, b1b = c1b * side;
            const uint32_t b2a = c2a * s2,   b2b = c2b * s2;
            idx0 = (c0a + b1a + b2a) + off;
            idx1 = (c0a + b1a + b2b) + off;
            idx2 = (c0a + b1b + b2a) + off;
            idx3 = (c0a + b1b + b2b) + off;
            idx4 = (c0b + b1a + b2a) + off;
            idx5 = (c0b + b1a + b2b) + off;
            idx6 = (c0b + b1b + b2a) + off;
            idx7 = (c0b + b1b + b2b) + off;
        }

        const float w0a = 1.0f - f0, w0b = f0;
        const float w1a = 1.0f - f1, w1b = f1;
        const float w2a = 1.0f - f2, w2b = f2;

        const float2 v0 = e2[idx0];
        const float2 v1 = e2[idx1];
        const float2 v2 = e2[idx2];
        const float2 v3 = e2[idx3];
        const float2 v4 = e2[idx4];
        const float2 v5 = e2[idx5];
        const float2 v6 = e2[idx6];
        const float2 v7 = e2[idx7];

        const float w000 = w0a * w1a * w2a;
        const float w001 = w0a * w1a * w2b;
        const float w010 = w0a * w1b * w2a;
        const float w011 = w0a * w1b * w2b;
        const float w100 = w0b * w1a * w2a;
        const float w101 = w0b * w1a * w2b;
        const float w110 = w0b * w1b * w2a;
        const float w111 = w0b * w1b * w2b;

        float sx = w000 * v0.x;
        float sy = w000 * v0.y;
        sx += w001 * v1.x;  sy += w001 * v1.y;
        sx += w010 * v2.x;  sy += w010 * v2.y;
        sx += w011 * v3.x;  sy += w011 * v3.y;
        sx += w100 * v4.x;  sy += w100 * v4.y;
        sx += w101 * v5.x;  sy += w101 * v5.y;
        sx += w110 * v6.x;  sy += w110 * v6.y;
        sx += w111 * v7.x;  sy += w111 * v7.y;

        float2 r; r.x = sx; r.y = sy;
        *(float2*)(outp + 2 * l) = r;
    }
}

extern "C" void kernel_launch(void* const* d_in, const int* in_sizes, int n_in,
                              void* d_out, int out_size, void* d_ws, size_t ws_size,
                              hipStream_t stream) {
    const float* inputs = (const float*)d_in[0];
    const float* emb    = (const float*)d_in[1];
    float* out          = (float*)d_out;

    // Mirror GridEncoder.__init__ level config in double precision.
    Params P;
    const double PLS = exp2(log2(2048.0 / 16.0) / 15.0); // per_level_scale
    uint64_t off = 0;
    for (int l = 0; l < NLVL; ++l) {
        const double s = 16.0 * pow(PLS, (double)l);
        const uint32_t side = (uint32_t)ceil(s) + 1u;
        const uint64_t s3 = (uint64_t)side * side * side;
        uint64_t params = s3 < (1ull << 19) ? s3 : (1ull << 19);
        params = (params + 7ull) / 8ull * 8ull; // align to 8
        P.scale[l]  = (float)(s - 1.0);
        P.side[l]   = side;
        P.offset[l] = (uint32_t)off;
        P.hashed[l] = (s3 > params) ? 1u : 0u;
        off += params;
    }

    const int npts = in_sizes[0] / 3; // 1048576
    dim3 grid(npts / 256), block(256);
    hipLaunchKernelGGL(grid_encode, grid, block, 0, stream, inputs, emb, out, P);
}

// Round 2
// 833.907 us; speedup vs baseline: 1.2985x; 1.2985x over previous
//
#include <hip/hip_runtime.h>
#include <cstdint>
#include <cmath>

#define NLVL 16
#define NDENSE 5

typedef float v2f __attribute__((ext_vector_type(2)));
typedef float v4f __attribute__((ext_vector_type(4)));

struct Params {
    float    scale[NLVL];
    uint32_t side[NLVL];
    uint32_t offset[NLVL];
    uint32_t hashed[NLVL];
};

struct DenseParams {
    float    scale[NDENSE];
    uint32_t side[NDENSE];
    uint32_t offset[NDENSE];
};

__device__ __forceinline__ uint32_t umin32(uint32_t a, uint32_t b) { return a < b ? a : b; }

// ---------- Phase kernel: one hashed level (size 2^19, mask 0x7FFFF) ----------
__global__ __launch_bounds__(256) void hash_level_kernel(
    const float* __restrict__ in, const v2f* __restrict__ emb2,
    v2f* __restrict__ wsl,              // ws + (size_t)l * npts
    float scale, uint32_t side, uint32_t off, uint32_t npts)
{
    const uint32_t i = blockIdx.x * 256u + threadIdx.x;
    if (i >= npts) return;
    const float x = __builtin_nontemporal_load(in + 3u * i + 0u);
    const float y = __builtin_nontemporal_load(in + 3u * i + 1u);
    const float z = __builtin_nontemporal_load(in + 3u * i + 2u);

    float p0 = x * scale + 0.5f, p1 = y * scale + 0.5f, p2 = z * scale + 0.5f;
    float fl0 = floorf(p0), fl1 = floorf(p1), fl2 = floorf(p2);
    float f0 = p0 - fl0, f1 = p1 - fl1, f2 = p2 - fl2;
    uint32_t g0 = (uint32_t)fl0, g1 = (uint32_t)fl1, g2 = (uint32_t)fl2;

    const uint32_t smax = side - 1u;
    uint32_t c0a = umin32(g0, smax), c0b = umin32(g0 + 1u, smax);
    uint32_t c1a = umin32(g1, smax), c1b = umin32(g1 + 1u, smax);
    uint32_t c2a = umin32(g2, smax), c2b = umin32(g2 + 1u, smax);

    const uint32_t h1a = c1a * 2654435761u, h1b = c1b * 2654435761u;
    const uint32_t h2a = c2a * 805459861u,  h2b = c2b * 805459861u;
    const uint32_t idx0 = ((c0a ^ h1a ^ h2a) & 0x7FFFFu) + off;
    const uint32_t idx1 = ((c0a ^ h1a ^ h2b) & 0x7FFFFu) + off;
    const uint32_t idx2 = ((c0a ^ h1b ^ h2a) & 0x7FFFFu) + off;
    const uint32_t idx3 = ((c0a ^ h1b ^ h2b) & 0x7FFFFu) + off;
    const uint32_t idx4 = ((c0b ^ h1a ^ h2a) & 0x7FFFFu) + off;
    const uint32_t idx5 = ((c0b ^ h1a ^ h2b) & 0x7FFFFu) + off;
    const uint32_t idx6 = ((c0b ^ h1b ^ h2a) & 0x7FFFFu) + off;
    const uint32_t idx7 = ((c0b ^ h1b ^ h2b) & 0x7FFFFu) + off;

    const v2f v0 = emb2[idx0], v1 = emb2[idx1], v2 = emb2[idx2], v3 = emb2[idx3];
    const v2f v4 = emb2[idx4], v5 = emb2[idx5], v6 = emb2[idx6], v7 = emb2[idx7];

    const float w0a = 1.0f - f0, w0b = f0;
    const float w1a = 1.0f - f1, w1b = f1;
    const float w2a = 1.0f - f2, w2b = f2;
    const float w000 = w0a * w1a * w2a, w001 = w0a * w1a * w2b;
    const float w010 = w0a * w1b * w2a, w011 = w0a * w1b * w2b;
    const float w100 = w0b * w1a * w2a, w101 = w0b * w1a * w2b;
    const float w110 = w0b * w1b * w2a, w111 = w0b * w1b * w2b;

    v2f r = w000 * v0 + w001 * v1 + w010 * v2 + w011 * v3
          + w100 * v4 + w101 * v5 + w110 * v6 + w111 * v7;
    __builtin_nontemporal_store(r, wsl + i);
}

// ---------- Dense levels 0..4 in one kernel (tables total ~2.8 MB) ----------
__global__ __launch_bounds__(256) void dense_levels_kernel(
    const float* __restrict__ in, const v2f* __restrict__ emb2,
    v2f* __restrict__ ws, uint32_t npts, DenseParams P)
{
    const uint32_t i = blockIdx.x * 256u + threadIdx.x;
    if (i >= npts) return;
    const float x = __builtin_nontemporal_load(in + 3u * i + 0u);
    const float y = __builtin_nontemporal_load(in + 3u * i + 1u);
    const float z = __builtin_nontemporal_load(in + 3u * i + 2u);

    #pragma unroll 1
    for (int l = 0; l < NDENSE; ++l) {
        const float scale = P.scale[l];
        const uint32_t side = P.side[l];
        const uint32_t off  = P.offset[l];

        float p0 = x * scale + 0.5f, p1 = y * scale + 0.5f, p2 = z * scale + 0.5f;
        float fl0 = floorf(p0), fl1 = floorf(p1), fl2 = floorf(p2);
        float f0 = p0 - fl0, f1 = p1 - fl1, f2 = p2 - fl2;
        uint32_t g0 = (uint32_t)fl0, g1 = (uint32_t)fl1, g2 = (uint32_t)fl2;

        const uint32_t smax = side - 1u;
        uint32_t c0a = umin32(g0, smax), c0b = umin32(g0 + 1u, smax);
        uint32_t c1a = umin32(g1, smax), c1b = umin32(g1 + 1u, smax);
        uint32_t c2a = umin32(g2, smax), c2b = umin32(g2 + 1u, smax);

        const uint32_t s2 = side * side;
        const uint32_t b1a = c1a * side, b1b = c1b * side;
        const uint32_t b2a = c2a * s2,   b2b = c2b * s2;
        const uint32_t idx0 = (c0a + b1a + b2a) + off;
        const uint32_t idx1 = (c0a + b1a + b2b) + off;
        const uint32_t idx2 = (c0a + b1b + b2a) + off;
        const uint32_t idx3 = (c0a + b1b + b2b) + off;
        const uint32_t idx4 = (c0b + b1a + b2a) + off;
        const uint32_t idx5 = (c0b + b1a + b2b) + off;
        const uint32_t idx6 = (c0b + b1b + b2a) + off;
        const uint32_t idx7 = (c0b + b1b + b2b) + off;

        const v2f v0 = emb2[idx0], v1 = emb2[idx1], v2 = emb2[idx2], v3 = emb2[idx3];
        const v2f v4 = emb2[idx4], v5 = emb2[idx5], v6 = emb2[idx6], v7 = emb2[idx7];

        const float w0a = 1.0f - f0, w0b = f0;
        const float w1a = 1.0f - f1, w1b = f1;
        const float w2a = 1.0f - f2, w2b = f2;
        v2f r = (w0a * w1a * w2a) * v0 + (w0a * w1a * w2b) * v1
              + (w0a * w1b * w2a) * v2 + (w0a * w1b * w2b) * v3
              + (w0b * w1a * w2a) * v4 + (w0b * w1a * w2b) * v5
              + (w0b * w1b * w2a) * v6 + (w0b * w1b * w2b) * v7;
        __builtin_nontemporal_store(r, ws + (size_t)l * npts + i);
    }
}

// ---------- Final pass: ws [NLVL][npts] float2 -> out [npts][32] ----------
__global__ __launch_bounds__(256) void interleave_kernel(
    const v2f* __restrict__ ws, float* __restrict__ out, uint32_t npts)
{
    const uint32_t i = blockIdx.x * 256u + threadIdx.x;
    if (i >= npts) return;
    v2f v[NLVL];
    #pragma unroll
    for (int l = 0; l < NLVL; ++l)
        v[l] = __builtin_nontemporal_load(ws + (size_t)l * npts + i);

    float* op = out + (size_t)i * 32u;
    #pragma unroll
    for (int l = 0; l < NLVL; l += 2) {
        v4f q;
        q.x = v[l].x;     q.y = v[l].y;
        q.z = v[l + 1].x; q.w = v[l + 1].y;
        __builtin_nontemporal_store(q, (v4f*)(op + 2 * l));
    }
}

// ---------- Fallback: round-1 monolithic kernel (used if ws too small) ----------
__global__ __launch_bounds__(256) void grid_encode_mono(
    const float* __restrict__ in, const float* __restrict__ emb,
    float* __restrict__ out, uint32_t npts, Params P)
{
    const uint32_t i = blockIdx.x * 256u + threadIdx.x;
    if (i >= npts) return;
    const float x = in[3u * i + 0u], y = in[3u * i + 1u], z = in[3u * i + 2u];
    const v2f* e2 = (const v2f*)emb;
    float* outp = out + (size_t)i * 32u;

    #pragma unroll 1
    for (int l = 0; l < NLVL; ++l) {
        const float scale = P.scale[l];
        const uint32_t side = P.side[l], off = P.offset[l], hashed = P.hashed[l];
        float p0 = x * scale + 0.5f, p1 = y * scale + 0.5f, p2 = z * scale + 0.5f;
        float fl0 = floorf(p0), fl1 = floorf(p1), fl2 = floorf(p2);
        float f0 = p0 - fl0, f1 = p1 - fl1, f2 = p2 - fl2;
        uint32_t g0 = (uint32_t)fl0, g1 = (uint32_t)fl1, g2 = (uint32_t)fl2;
        const uint32_t smax = side - 1u;
        uint32_t c0a = umin32(g0, smax), c0b = umin32(g0 + 1u, smax);
        uint32_t c1a = umin32(g1, smax), c1b = umin32(g1 + 1u, smax);
        uint32_t c2a = umin32(g2, smax), c2b = umin32(g2 + 1u, smax);
        uint32_t idx0, idx1, idx2, idx3, idx4, idx5, idx6, idx7;
        if (hashed) {
            const uint32_t h1a = c1a * 2654435761u, h1b = c1b * 2654435761u;
            const uint32_t h2a = c2a * 805459861u,  h2b = c2b * 805459861u;
            idx0 = ((c0a ^ h1a ^ h2a) & 0x7FFFFu) + off;
            idx1 = ((c0a ^ h1a ^ h2b) & 0x7FFFFu) + off;
            idx2 = ((c0a ^ h1b ^ h2a) & 0x7FFFFu) + off;
            idx3 = ((c0a ^ h1b ^ h2b) & 0x7FFFFu) + off;
            idx4 = ((c0b ^ h1a ^ h2a) & 0x7FFFFu) + off;
            idx5 = ((c0b ^ h1a ^ h2b) & 0x7FFFFu) + off;
            idx6 = ((c0b ^ h1b ^ h2a) & 0x7FFFFu) + off;
            idx7 = ((c0b ^ h1b ^ h2b) & 0x7FFFFu) + off;
        } else {
            const uint32_t s2 = side * side;
            const uint32_t b1a = c1a * side, b1b = c1b * side;
            const uint32_t b2a = c2a * s2,   b2b = c2b * s2;
            idx0 = (c0a + b1a + b2a) + off; idx1 = (c0a + b1a + b2b) + off;
            idx2 = (c0a + b1b + b2a) + off; idx3 = (c0a + b1b + b2b) + off;
            idx4 = (c0b + b1a + b2a) + off; idx5 = (c0b + b1a + b2b) + off;
            idx6 = (c0b + b1b + b2a) + off; idx7 = (c0b + b1b + b2b) + off;
        }
        const v2f v0 = e2[idx0], v1 = e2[idx1], v2 = e2[idx2], v3 = e2[idx3];
        const v2f v4 = e2[idx4], v5 = e2[idx5], v6 = e2[idx6], v7 = e2[idx7];
        const float w0a = 1.0f - f0, w0b = f0;
        const float w1a = 1.0f - f1, w1b = f1;
        const float w2a = 1.0f - f2, w2b = f2;
        v2f r = (w0a*w1a*w2a) * v0 + (w0a*w1a*w2b) * v1 + (w0a*w1b*w2a) * v2 + (w0a*w1b*w2b) * v3
              + (w0b*w1a*w2a) * v4 + (w0b*w1a*w2b) * v5 + (w0b*w1b*w2a) * v6 + (w0b*w1b*w2b) * v7;
        *(v2f*)(outp + 2 * l) = r;
    }
}

extern "C" void kernel_launch(void* const* d_in, const int* in_sizes, int n_in,
                              void* d_out, int out_size, void* d_ws, size_t ws_size,
                              hipStream_t stream) {
    const float* inputs = (const float*)d_in[0];
    const float* emb    = (const float*)d_in[1];
    float* out          = (float*)d_out;

    // Mirror GridEncoder.__init__ level config in double precision.
    Params P;
    DenseParams DP;
    const double PLS = exp2(log2(2048.0 / 16.0) / 15.0);
    uint64_t off = 0;
    for (int l = 0; l < NLVL; ++l) {
        const double s = 16.0 * pow(PLS, (double)l);
        const uint32_t side = (uint32_t)ceil(s) + 1u;
        const uint64_t s3 = (uint64_t)side * side * side;
        uint64_t params = s3 < (1ull << 19) ? s3 : (1ull << 19);
        params = (params + 7ull) / 8ull * 8ull;
        P.scale[l]  = (float)(s - 1.0);
        P.side[l]   = side;
        P.offset[l] = (uint32_t)off;
        P.hashed[l] = (s3 > params) ? 1u : 0u;
        if (l < NDENSE) { DP.scale[l] = P.scale[l]; DP.side[l] = P.side[l]; DP.offset[l] = P.offset[l]; }
        off += params;
    }

    const uint32_t npts = (uint32_t)(in_sizes[0] / 3);
    const uint32_t nblk = (npts + 255u) / 256u;
    const size_t ws_needed = (size_t)NLVL * npts * sizeof(v2f);

    if (ws_size >= ws_needed) {
        v2f* ws = (v2f*)d_ws;
        const v2f* emb2 = (const v2f*)emb;
        // dense levels 0..4 (one kernel)
        hipLaunchKernelGGL(dense_levels_kernel, dim3(nblk), dim3(256), 0, stream,
                           inputs, emb2, ws, npts, DP);
        // hashed levels 5..15, one kernel each (temporal phasing for L2 residency)
        for (int l = NDENSE; l < NLVL; ++l) {
            hipLaunchKernelGGL(hash_level_kernel, dim3(nblk), dim3(256), 0, stream,
                               inputs, emb2, ws + (size_t)l * npts,
                               P.scale[l], P.side[l], P.offset[l], npts);
        }
        // interleave ws -> out
        hipLaunchKernelGGL(interleave_kernel, dim3(nblk), dim3(256), 0, stream,
                           ws, out, npts);
    } else {
        hipLaunchKernelGGL(grid_encode_mono, dim3(nblk), dim3(256), 0, stream,
                           inputs, emb, out, npts, P);
    }
}

// Round 3
// 527.007 us; speedup vs baseline: 2.0547x; 1.5823x over previous
//
#include <hip/hip_runtime.h>
#include <cstdint>
#include <cmath>

#define NLVL 16
#define NDENSE 5

typedef float v2f __attribute__((ext_vector_type(2)));
typedef float v4f __attribute__((ext_vector_type(4)));

struct Params {
    float    scale[NLVL];
    uint32_t side[NLVL];
    uint32_t offset[NLVL];
    uint32_t hashed[NLVL];
};

struct DenseParams {
    float    scale[NDENSE];
    uint32_t side[NDENSE];
    uint32_t offset[NDENSE];
};

__device__ __forceinline__ uint32_t umin32(uint32_t a, uint32_t b) { return a < b ? a : b; }

// Load the corner pair (ia, ib). When they form an aligned even/odd pair
// (always the case when c0a is even, since ib = ia^1 under the xor-hash),
// ONE dwordx4 load serves both corners; otherwise a lane-predicated v2f
// load fetches corner b (masked-off lanes issue no L2 request).
__device__ __forceinline__ void pair_load(const float* __restrict__ embf,
                                          uint32_t ia, uint32_t ib,
                                          v2f& va, v2f& vb) {
    const v4f q = *(const v4f*)(embf + 2u * (ia & ~1u));
    v2f lo; lo.x = q.x; lo.y = q.y;
    v2f hi; hi.x = q.z; hi.y = q.w;
    va = (ia & 1u) ? hi : lo;
    if ((ia ^ ib) > 1u) {
        vb = *(const v2f*)(embf + 2u * ib);   // predicated: only unpaired lanes
    } else {
        vb = (ib & 1u) ? hi : lo;
    }
}

// ---------- Phase kernel: one hashed level (size 2^19, mask 0x7FFFF) ----------
__global__ __launch_bounds__(256) void hash_level_kernel(
    const float* __restrict__ in, const float* __restrict__ embf,
    v2f* __restrict__ wsl, float scale, uint32_t side, uint32_t off, uint32_t npts)
{
    const uint32_t i = blockIdx.x * 256u + threadIdx.x;
    if (i >= npts) return;
    const float x = in[3u * i + 0u];
    const float y = in[3u * i + 1u];
    const float z = in[3u * i + 2u];

    float p0 = x * scale + 0.5f, p1 = y * scale + 0.5f, p2 = z * scale + 0.5f;
    float fl0 = floorf(p0), fl1 = floorf(p1), fl2 = floorf(p2);
    float f0 = p0 - fl0, f1 = p1 - fl1, f2 = p2 - fl2;
    uint32_t g0 = (uint32_t)fl0, g1 = (uint32_t)fl1, g2 = (uint32_t)fl2;

    const uint32_t smax = side - 1u;
    uint32_t c0a = umin32(g0, smax), c0b = umin32(g0 + 1u, smax);
    uint32_t c1a = umin32(g1, smax), c1b = umin32(g1 + 1u, smax);
    uint32_t c2a = umin32(g2, smax), c2b = umin32(g2 + 1u, smax);

    const uint32_t h1a = c1a * 2654435761u, h1b = c1b * 2654435761u;
    const uint32_t h2a = c2a * 805459861u,  h2b = c2b * 805459861u;
    const uint32_t idx0 = ((c0a ^ h1a ^ h2a) & 0x7FFFFu) + off;
    const uint32_t idx1 = ((c0a ^ h1a ^ h2b) & 0x7FFFFu) + off;
    const uint32_t idx2 = ((c0a ^ h1b ^ h2a) & 0x7FFFFu) + off;
    const uint32_t idx3 = ((c0a ^ h1b ^ h2b) & 0x7FFFFu) + off;
    const uint32_t idx4 = ((c0b ^ h1a ^ h2a) & 0x7FFFFu) + off;
    const uint32_t idx5 = ((c0b ^ h1a ^ h2b) & 0x7FFFFu) + off;
    const uint32_t idx6 = ((c0b ^ h1b ^ h2a) & 0x7FFFFu) + off;
    const uint32_t idx7 = ((c0b ^ h1b ^ h2b) & 0x7FFFFu) + off;

    // 4 corner pairs differing only in the x-coordinate
    v2f v0, v1, v2, v3, v4, v5, v6, v7;
    pair_load(embf, idx0, idx4, v0, v4);
    pair_load(embf, idx1, idx5, v1, v5);
    pair_load(embf, idx2, idx6, v2, v6);
    pair_load(embf, idx3, idx7, v3, v7);

    const float w0a = 1.0f - f0, w0b = f0;
    const float w1a = 1.0f - f1, w1b = f1;
    const float w2a = 1.0f - f2, w2b = f2;
    v2f r = (w0a * w1a * w2a) * v0 + (w0a * w1a * w2b) * v1
          + (w0a * w1b * w2a) * v2 + (w0a * w1b * w2b) * v3
          + (w0b * w1a * w2a) * v4 + (w0b * w1a * w2b) * v5
          + (w0b * w1b * w2a) * v6 + (w0b * w1b * w2b) * v7;
    __builtin_nontemporal_store(r, wsl + i);
}

// ---------- Finalize: dense levels inline + ws hashed levels -> out, coalesced ----------
__global__ __launch_bounds__(256) void finalize_kernel(
    const float* __restrict__ in, const v2f* __restrict__ emb2,
    const v2f* __restrict__ ws, float* __restrict__ out,
    uint32_t npts, DenseParams P)
{
    __shared__ float lds[256 * 33];   // +1 float pad per 32-float row: conflict-free
    const uint32_t t = threadIdx.x;
    const uint32_t i = blockIdx.x * 256u + t;

    const float x = in[3u * i + 0u];
    const float y = in[3u * i + 1u];
    const float z = in[3u * i + 2u];
    float* row = lds + t * 33u;

    // dense levels 0..4: tables total ~2.8 MB, L2-resident
    #pragma unroll 1
    for (int l = 0; l < NDENSE; ++l) {
        const float scale = P.scale[l];
        const uint32_t side = P.side[l];
        const uint32_t off  = P.offset[l];

        float p0 = x * scale + 0.5f, p1 = y * scale + 0.5f, p2 = z * scale + 0.5f;
        float fl0 = floorf(p0), fl1 = floorf(p1), fl2 = floorf(p2);
        float f0 = p0 - fl0, f1 = p1 - fl1, f2 = p2 - fl2;
        uint32_t g0 = (uint32_t)fl0, g1 = (uint32_t)fl1, g2 = (uint32_t)fl2;

        const uint32_t smax = side - 1u;
        uint32_t c0a = umin32(g0, smax), c0b = umin32(g0 + 1u, smax);
        uint32_t c1a = umin32(g1, smax), c1b = umin32(g1 + 1u, smax);
        uint32_t c2a = umin32(g2, smax), c2b = umin32(g2 + 1u, smax);

        const uint32_t s2 = side * side;
        const uint32_t b1a = c1a * side, b1b = c1b * side;
        const uint32_t b2a = c2a * s2,   b2b = c2b * s2;
        const v2f v0 = emb2[(c0a + b1a + b2a) + off];
        const v2f v1 = emb2[(c0a + b1a + b2b) + off];
        const v2f v2 = emb2[(c0a + b1b + b2a) + off];
        const v2f v3 = emb2[(c0a + b1b + b2b) + off];
        const v2f v4 = emb2[(c0b + b1a + b2a) + off];
        const v2f v5 = emb2[(c0b + b1a + b2b) + off];
        const v2f v6 = emb2[(c0b + b1b + b2a) + off];
        const v2f v7 = emb2[(c0b + b1b + b2b) + off];

        const float w0a = 1.0f - f0, w0b = f0;
        const float w1a = 1.0f - f1, w1b = f1;
        const float w2a = 1.0f - f2, w2b = f2;
        v2f r = (w0a * w1a * w2a) * v0 + (w0a * w1a * w2b) * v1
              + (w0a * w1b * w2a) * v2 + (w0a * w1b * w2b) * v3
              + (w0b * w1a * w2a) * v4 + (w0b * w1a * w2b) * v5
              + (w0b * w1b * w2a) * v6 + (w0b * w1b * w2b) * v7;
        row[2 * l]     = r.x;
        row[2 * l + 1] = r.y;
    }

    // hashed levels 5..15 from workspace (coalesced reads)
    #pragma unroll
    for (int l = NDENSE; l < NLVL; ++l) {
        v2f r = __builtin_nontemporal_load(ws + (size_t)(l - NDENSE) * npts + i);
        row[2 * l]     = r.x;
        row[2 * l + 1] = r.y;
    }

    __syncthreads();

    // coalesced output: each block writes its 32768-float chunk contiguously
    float* obase = out + (size_t)blockIdx.x * 256u * 32u;
    #pragma unroll
    for (int k = 0; k < 8; ++k) {
        const uint32_t f = (uint32_t)k * 1024u + t * 4u;   // float idx in chunk
        const uint32_t p = f >> 5, c = f & 31u;
        const float* src = lds + p * 33u + c;
        v4f q; q.x = src[0]; q.y = src[1]; q.z = src[2]; q.w = src[3];
        __builtin_nontemporal_store(q, (v4f*)(obase + f));
    }
}

// ---------- Fallback: monolithic kernel (used if ws too small) ----------
__global__ __launch_bounds__(256) void grid_encode_mono(
    const float* __restrict__ in, const float* __restrict__ emb,
    float* __restrict__ out, uint32_t npts, Params P)
{
    const uint32_t i = blockIdx.x * 256u + threadIdx.x;
    if (i >= npts) return;
    const float x = in[3u * i + 0u], y = in[3u * i + 1u], z = in[3u * i + 2u];
    const v2f* e2 = (const v2f*)emb;
    float* outp = out + (size_t)i * 32u;

    #pragma unroll 1
    for (int l = 0; l < NLVL; ++l) {
        const float scale = P.scale[l];
        const uint32_t side = P.side[l], off = P.offset[l], hashed = P.hashed[l];
        float p0 = x * scale + 0.5f, p1 = y * scale + 0.5f, p2 = z * scale + 0.5f;
        float fl0 = floorf(p0), fl1 = floorf(p1), fl2 = floorf(p2);
        float f0 = p0 - fl0, f1 = p1 - fl1, f2 = p2 - fl2;
        uint32_t g0 = (uint32_t)fl0, g1 = (uint32_t)fl1, g2 = (uint32_t)fl2;
        const uint32_t smax = side - 1u;
        uint32_t c0a = umin32(g0, smax), c0b = umin32(g0 + 1u, smax);
        uint32_t c1a = umin32(g1, smax), c1b = umin32(g1 + 1u, smax);
        uint32_t c2a = umin32(g2, smax), c2b = umin32(g2 + 1u, smax);
        uint32_t idx0, idx1, idx2, idx3, idx4, idx5, idx6, idx7;
        if (hashed) {
            const uint32_t h1a = c1a * 2654435761u, h1b = c1b * 2654435761u;
            const uint32_t h2a = c2a * 805459861u,  h2b = c2b * 805459861u;
            idx0 = ((c0a ^ h1a ^ h2a) & 0x7FFFFu) + off;
            idx1 = ((c0a ^ h1a ^ h2b) & 0x7FFFFu) + off;
            idx2 = ((c0a ^ h1b ^ h2a) & 0x7FFFFu) + off;
            idx3 = ((c0a ^ h1b ^ h2b) & 0x7FFFFu) + off;
            idx4 = ((c0b ^ h1a ^ h2a) & 0x7FFFFu) + off;
            idx5 = ((c0b ^ h1a ^ h2b) & 0x7FFFFu) + off;
            idx6 = ((c0b ^ h1b ^ h2a) & 0x7FFFFu) + off;
            idx7 = ((c0b ^ h1b ^ h2b) & 0x7FFFFu) + off;
        } else {
            const uint32_t s2 = side * side;
            const uint32_t b1a = c1a * side, b1b = c1b * side;
            const uint32_t b2a = c2a * s2,   b2b = c2b * s2;
            idx0 = (c0a + b1a + b2a) + off; idx1 = (c0a + b1a + b2b) + off;
            idx2 = (c0a + b1b + b2a) + off; idx3 = (c0a + b1b + b2b) + off;
            idx4 = (c0b + b1a + b2a) + off; idx5 = (c0b + b1a + b2b) + off;
            idx6 = (c0b + b1b + b2a) + off; idx7 = (c0b + b1b + b2b) + off;
        }
        const v2f v0 = e2[idx0], v1 = e2[idx1], v2 = e2[idx2], v3 = e2[idx3];
        const v2f v4 = e2[idx4], v5 = e2[idx5], v6 = e2[idx6], v7 = e2[idx7];
        const float w0a = 1.0f - f0, w0b = f0;
        const float w1a = 1.0f - f1, w1b = f1;
        const float w2a = 1.0f - f2, w2b = f2;
        v2f r = (w0a*w1a*w2a) * v0 + (w0a*w1a*w2b) * v1 + (w0a*w1b*w2a) * v2 + (w0a*w1b*w2b) * v3
              + (w0b*w1a*w2a) * v4 + (w0b*w1a*w2b) * v5 + (w0b*w1b*w2a) * v6 + (w0b*w1b*w2b) * v7;
        *(v2f*)(outp + 2 * l) = r;
    }
}

extern "C" void kernel_launch(void* const* d_in, const int* in_sizes, int n_in,
                              void* d_out, int out_size, void* d_ws, size_t ws_size,
                              hipStream_t stream) {
    const float* inputs = (const float*)d_in[0];
    const float* emb    = (const float*)d_in[1];
    float* out          = (float*)d_out;

    // Mirror GridEncoder.__init__ level config in double precision (matches numpy).
    Params P;
    DenseParams DP;
    const double PLS = exp2(log2(2048.0 / 16.0) / 15.0);
    uint64_t off = 0;
    for (int l = 0; l < NLVL; ++l) {
        const double s = 16.0 * pow(PLS, (double)l);
        const uint32_t side = (uint32_t)ceil(s) + 1u;
        const uint64_t s3 = (uint64_t)side * side * side;
        uint64_t params = s3 < (1ull << 19) ? s3 : (1ull << 19);
        params = (params + 7ull) / 8ull * 8ull;
        P.scale[l]  = (float)(s - 1.0);
        P.side[l]   = side;
        P.offset[l] = (uint32_t)off;
        P.hashed[l] = (s3 > params) ? 1u : 0u;
        if (l < NDENSE) { DP.scale[l] = P.scale[l]; DP.side[l] = P.side[l]; DP.offset[l] = P.offset[l]; }
        off += params;
    }

    const uint32_t npts = (uint32_t)(in_sizes[0] / 3);
    const uint32_t nblk = (npts + 255u) / 256u;
    const size_t ws_needed = (size_t)(NLVL - NDENSE) * npts * sizeof(v2f);

    if (ws_size >= ws_needed && (npts % 256u) == 0u) {
        v2f* ws = (v2f*)d_ws;
        // hashed levels 5..15, one kernel each (temporal phasing for L2 residency)
        for (int l = NDENSE; l < NLVL; ++l) {
            hipLaunchKernelGGL(hash_level_kernel, dim3(nblk), dim3(256), 0, stream,
                               inputs, emb, ws + (size_t)(l - NDENSE) * npts,
                               P.scale[l], P.side[l], P.offset[l], npts);
        }
        // dense levels + interleave + coalesced write
        hipLaunchKernelGGL(finalize_kernel, dim3(nblk), dim3(256), 0, stream,
                           inputs, (const v2f*)emb, ws, out, npts, DP);
    } else {
        hipLaunchKernelGGL(grid_encode_mono, dim3(nblk), dim3(256), 0, stream,
                           inputs, emb, out, npts, P);
    }
}

// Round 4
// 472.161 us; speedup vs baseline: 2.2934x; 1.1162x over previous
//
#include <hip/hip_runtime.h>
#include <cstdint>
#include <cmath>

#define NLVL 16
#define NDENSE 5

typedef float v2f __attribute__((ext_vector_type(2)));
typedef float v4f __attribute__((ext_vector_type(4)));
typedef float v4f8 __attribute__((ext_vector_type(4), aligned(8)));  // 8B-aligned float4

struct Params {
    float    scale[NLVL];
    uint32_t side[NLVL];
    uint32_t offset[NLVL];
    uint32_t hashed[NLVL];
};

struct DenseParams {
    float    scale[NDENSE];
    uint32_t side[NDENSE];
    uint32_t offset[NDENSE];
};

__device__ __forceinline__ uint32_t umin32(uint32_t a, uint32_t b) { return a < b ? a : b; }

// Hashed-level corner pair (ia, ib = ia with x+1 hashed): adjacent even/odd pair
// iff c0a even -> one aligned dwordx4 serves both; else predicated v2f for b.
__device__ __forceinline__ void pair_load(const float* __restrict__ embf,
                                          uint32_t ia, uint32_t ib,
                                          v2f& va, v2f& vb) {
    const v4f q = *(const v4f*)(embf + 2u * (ia & ~1u));
    v2f lo; lo.x = q.x; lo.y = q.y;
    v2f hi; hi.x = q.z; hi.y = q.w;
    va = (ia & 1u) ? hi : lo;
    if ((ia ^ ib) > 1u) {
        vb = *(const v2f*)(embf + 2u * ib);   // predicated: only unpaired lanes
    } else {
        vb = (ib & 1u) ? hi : lo;
    }
}

// Dense-level x-pair: corners are CONTIGUOUS (ib = ia+1, or clamped ib = ia).
// One (possibly 8B-aligned) 16B load covers both; clamp is a register select.
// Reading embf[2*ia .. 2*ia+3] stays in-bounds: ia+1 <= level size (align-8) or
// spills into the next level's table, and the hi half is discarded via select.
__device__ __forceinline__ void dense_pair_load(const float* __restrict__ embf,
                                                uint32_t ia, uint32_t clamped,
                                                v2f& va, v2f& vb) {
    const v4f8 q = *(const v4f8*)(embf + 2u * ia);
    va.x = q.x; va.y = q.y;
    v2f hi; hi.x = q.z; hi.y = q.w;
    vb = clamped ? va : hi;
}

// ---------- Phase kernel: one hashed level (size 2^19, mask 0x7FFFF) ----------
__global__ __launch_bounds__(256) void hash_level_kernel(
    const float* __restrict__ in, const float* __restrict__ embf,
    v2f* __restrict__ wsl, float scale, uint32_t side, uint32_t off, uint32_t npts)
{
    const uint32_t i = blockIdx.x * 256u + threadIdx.x;
    if (i >= npts) return;
    const float x = in[3u * i + 0u];
    const float y = in[3u * i + 1u];
    const float z = in[3u * i + 2u];

    float p0 = x * scale + 0.5f, p1 = y * scale + 0.5f, p2 = z * scale + 0.5f;
    float fl0 = floorf(p0), fl1 = floorf(p1), fl2 = floorf(p2);
    float f0 = p0 - fl0, f1 = p1 - fl1, f2 = p2 - fl2;
    uint32_t g0 = (uint32_t)fl0, g1 = (uint32_t)fl1, g2 = (uint32_t)fl2;

    const uint32_t smax = side - 1u;
    uint32_t c0a = umin32(g0, smax), c0b = umin32(g0 + 1u, smax);
    uint32_t c1a = umin32(g1, smax), c1b = umin32(g1 + 1u, smax);
    uint32_t c2a = umin32(g2, smax), c2b = umin32(g2 + 1u, smax);

    const uint32_t h1a = c1a * 2654435761u, h1b = c1b * 2654435761u;
    const uint32_t h2a = c2a * 805459861u,  h2b = c2b * 805459861u;
    const uint32_t idx0 = ((c0a ^ h1a ^ h2a) & 0x7FFFFu) + off;
    const uint32_t idx1 = ((c0a ^ h1a ^ h2b) & 0x7FFFFu) + off;
    const uint32_t idx2 = ((c0a ^ h1b ^ h2a) & 0x7FFFFu) + off;
    const uint32_t idx3 = ((c0a ^ h1b ^ h2b) & 0x7FFFFu) + off;
    const uint32_t idx4 = ((c0b ^ h1a ^ h2a) & 0x7FFFFu) + off;
    const uint32_t idx5 = ((c0b ^ h1a ^ h2b) & 0x7FFFFu) + off;
    const uint32_t idx6 = ((c0b ^ h1b ^ h2a) & 0x7FFFFu) + off;
    const uint32_t idx7 = ((c0b ^ h1b ^ h2b) & 0x7FFFFu) + off;

    v2f v0, v1, v2, v3, v4, v5, v6, v7;
    pair_load(embf, idx0, idx4, v0, v4);
    pair_load(embf, idx1, idx5, v1, v5);
    pair_load(embf, idx2, idx6, v2, v6);
    pair_load(embf, idx3, idx7, v3, v7);

    const float w0a = 1.0f - f0, w0b = f0;
    const float w1a = 1.0f - f1, w1b = f1;
    const float w2a = 1.0f - f2, w2b = f2;
    v2f r = (w0a * w1a * w2a) * v0 + (w0a * w1a * w2b) * v1
          + (w0a * w1b * w2a) * v2 + (w0a * w1b * w2b) * v3
          + (w0b * w1a * w2a) * v4 + (w0b * w1a * w2b) * v5
          + (w0b * w1b * w2a) * v6 + (w0b * w1b * w2b) * v7;
    __builtin_nontemporal_store(r, wsl + i);
}

// ---------- Finalize: dense levels inline + ws hashed levels -> out, coalesced ----------
__global__ __launch_bounds__(256) void finalize_kernel(
    const float* __restrict__ in, const float* __restrict__ embf,
    const v2f* __restrict__ ws, float* __restrict__ out,
    uint32_t npts, DenseParams P)
{
    __shared__ float lds[256 * 33];   // +1 float pad per 32-float row: conflict-free
    const uint32_t t = threadIdx.x;
    const uint32_t i = blockIdx.x * 256u + t;

    const float x = in[3u * i + 0u];
    const float y = in[3u * i + 1u];
    const float z = in[3u * i + 2u];
    float* row = lds + t * 33u;

    // dense levels 0..4: tables total ~2.8 MB, L2-resident; full unroll for MLP
    #pragma unroll
    for (int l = 0; l < NDENSE; ++l) {
        const float scale = P.scale[l];
        const uint32_t side = P.side[l];
        const uint32_t off  = P.offset[l];

        float p0 = x * scale + 0.5f, p1 = y * scale + 0.5f, p2 = z * scale + 0.5f;
        float fl0 = floorf(p0), fl1 = floorf(p1), fl2 = floorf(p2);
        float f0 = p0 - fl0, f1 = p1 - fl1, f2 = p2 - fl2;
        uint32_t g0 = (uint32_t)fl0, g1 = (uint32_t)fl1, g2 = (uint32_t)fl2;

        const uint32_t smax = side - 1u;
        uint32_t c0a = umin32(g0, smax);
        const uint32_t clamped = (c0a == smax) ? 1u : 0u;   // c0b == c0a
        uint32_t c1a = umin32(g1, smax), c1b = umin32(g1 + 1u, smax);
        uint32_t c2a = umin32(g2, smax), c2b = umin32(g2 + 1u, smax);

        const uint32_t s2 = side * side;
        const uint32_t b1a = c1a * side, b1b = c1b * side;
        const uint32_t b2a = c2a * s2,   b2b = c2b * s2;

        // 4 contiguous x-pairs -> 4 16B loads (instead of 8 8B gathers)
        v2f v0, v1, v2, v3, v4, v5, v6, v7;
        dense_pair_load(embf, c0a + b1a + b2a + off, clamped, v0, v4);
        dense_pair_load(embf, c0a + b1a + b2b + off, clamped, v1, v5);
        dense_pair_load(embf, c0a + b1b + b2a + off, clamped, v2, v6);
        dense_pair_load(embf, c0a + b1b + b2b + off, clamped, v3, v7);

        const float w0a = 1.0f - f0, w0b = f0;
        const float w1a = 1.0f - f1, w1b = f1;
        const float w2a = 1.0f - f2, w2b = f2;
        v2f r = (w0a * w1a * w2a) * v0 + (w0a * w1a * w2b) * v1
              + (w0a * w1b * w2a) * v2 + (w0a * w1b * w2b) * v3
              + (w0b * w1a * w2a) * v4 + (w0b * w1a * w2b) * v5
              + (w0b * w1b * w2a) * v6 + (w0b * w1b * w2b) * v7;
        row[2 * l]     = r.x;
        row[2 * l + 1] = r.y;
    }

    // hashed levels 5..15 from workspace (coalesced reads)
    #pragma unroll
    for (int l = NDENSE; l < NLVL; ++l) {
        v2f r = __builtin_nontemporal_load(ws + (size_t)(l - NDENSE) * npts + i);
        row[2 * l]     = r.x;
        row[2 * l + 1] = r.y;
    }

    __syncthreads();

    // coalesced output: each block writes its 32768-float chunk contiguously
    float* obase = out + (size_t)blockIdx.x * 256u * 32u;
    #pragma unroll
    for (int k = 0; k < 8; ++k) {
        const uint32_t f = (uint32_t)k * 1024u + t * 4u;   // float idx in chunk
        const uint32_t p = f >> 5, c = f & 31u;
        const float* src = lds + p * 33u + c;
        v4f q; q.x = src[0]; q.y = src[1]; q.z = src[2]; q.w = src[3];
        __builtin_nontemporal_store(q, (v4f*)(obase + f));
    }
}

// ---------- Fallback: monolithic kernel (used if ws too small) ----------
__global__ __launch_bounds__(256) void grid_encode_mono(
    const float* __restrict__ in, const float* __restrict__ emb,
    float* __restrict__ out, uint32_t npts, Params P)
{
    const uint32_t i = blockIdx.x * 256u + threadIdx.x;
    if (i >= npts) return;
    const float x = in[3u * i + 0u], y = in[3u * i + 1u], z = in[3u * i + 2u];
    const v2f* e2 = (const v2f*)emb;
    float* outp = out + (size_t)i * 32u;

    #pragma unroll 1
    for (int l = 0; l < NLVL; ++l) {
        const float scale = P.scale[l];
        const uint32_t side = P.side[l], off = P.offset[l], hashed = P.hashed[l];
        float p0 = x * scale + 0.5f, p1 = y * scale + 0.5f, p2 = z * scale + 0.5f;
        float fl0 = floorf(p0), fl1 = floorf(p1), fl2 = floorf(p2);
        float f0 = p0 - fl0, f1 = p1 - fl1, f2 = p2 - fl2;
        uint32_t g0 = (uint32_t)fl0, g1 = (uint32_t)fl1, g2 = (uint32_t)fl2;
        const uint32_t smax = side - 1u;
        uint32_t c0a = umin32(g0, smax), c0b = umin32(g0 + 1u, smax);
        uint32_t c1a = umin32(g1, smax), c1b = umin32(g1 + 1u, smax);
        uint32_t c2a = umin32(g2, smax), c2b = umin32(g2 + 1u, smax);
        uint32_t idx0, idx1, idx2, idx3, idx4, idx5, idx6, idx7;
        if (hashed) {
            const uint32_t h1a = c1a * 2654435761u, h1b = c1b * 2654435761u;
            const uint32_t h2a = c2a * 805459861u,  h2b = c2b * 805459861u;
            idx0 = ((c0a ^ h1a ^ h2a) & 0x7FFFFu) + off;
            idx1 = ((c0a ^ h1a ^ h2b) & 0x7FFFFu) + off;
            idx2 = ((c0a ^ h1b ^ h2a) & 0x7FFFFu) + off;
            idx3 = ((c0a ^ h1b ^ h2b) & 0x7FFFFu) + off;
            idx4 = ((c0b ^ h1a ^ h2a) & 0x7FFFFu) + off;
            idx5 = ((c0b ^ h1a ^ h2b) & 0x7FFFFu) + off;
            idx6 = ((c0b ^ h1b ^ h2a) & 0x7FFFFu) + off;
            idx7 = ((c0b ^ h1b ^ h2b) & 0x7FFFFu) + off;
        } else {
            const uint32_t s2 = side * side;
            const uint32_t b1a = c1a * side, b1b = c1b * side;
            const uint32_t b2a = c2a * s2,   b2b = c2b * s2;
            idx0 = (c0a + b1a + b2a) + off; idx1 = (c0a + b1a + b2b) + off;
            idx2 = (c0a + b1b + b2a) + off; idx3 = (c0a + b1b + b2b) + off;
            idx4 = (c0b + b1a + b2a) + off; idx5 = (c0b + b1a + b2b) + off;
            idx6 = (c0b + b1b + b2a) + off; idx7 = (c0b + b1b + b2b) + off;
        }
        const v2f v0 = e2[idx0], v1 = e2[idx1], v2 = e2[idx2], v3 = e2[idx3];
        const v2f v4 = e2[idx4], v5 = e2[idx5], v6 = e2[idx6], v7 = e2[idx7];
        const float w0a = 1.0f - f0, w0b = f0;
        const float w1a = 1.0f - f1, w1b = f1;
        const float w2a = 1.0f - f2, w2b = f2;
        v2f r = (w0a*w1a*w2a) * v0 + (w0a*w1a*w2b) * v1 + (w0a*w1b*w2a) * v2 + (w0a*w1b*w2b) * v3
              + (w0b*w1a*w2a) * v4 + (w0b*w1a*w2b) * v5 + (w0b*w1b*w2a) * v6 + (w0b*w1b*w2b) * v7;
        *(v2f*)(outp + 2 * l) = r;
    }
}

extern "C" void kernel_launch(void* const* d_in, const int* in_sizes, int n_in,
                              void* d_out, int out_size, void* d_ws, size_t ws_size,
                              hipStream_t stream) {
    const float* inputs = (const float*)d_in[0];
    const float* emb    = (const float*)d_in[1];
    float* out          = (float*)d_out;

    // Mirror GridEncoder.__init__ level config in double precision (matches numpy).
    Params P;
    DenseParams DP;
    const double PLS = exp2(log2(2048.0 / 16.0) / 15.0);
    uint64_t off = 0;
    for (int l = 0; l < NLVL; ++l) {
        const double s = 16.0 * pow(PLS, (double)l);
        const uint32_t side = (uint32_t)ceil(s) + 1u;
        const uint64_t s3 = (uint64_t)side * side * side;
        uint64_t params = s3 < (1ull << 19) ? s3 : (1ull << 19);
        params = (params + 7ull) / 8ull * 8ull;
        P.scale[l]  = (float)(s - 1.0);
        P.side[l]   = side;
        P.offset[l] = (uint32_t)off;
        P.hashed[l] = (s3 > params) ? 1u : 0u;
        if (l < NDENSE) { DP.scale[l] = P.scale[l]; DP.side[l] = P.side[l]; DP.offset[l] = P.offset[l]; }
        off += params;
    }

    const uint32_t npts = (uint32_t)(in_sizes[0] / 3);
    const uint32_t nblk = (npts + 255u) / 256u;
    const size_t ws_needed = (size_t)(NLVL - NDENSE) * npts * sizeof(v2f);

    if (ws_size >= ws_needed && (npts % 256u) == 0u) {
        v2f* ws = (v2f*)d_ws;
        // hashed levels 5..15, one kernel each (temporal phasing for L2 residency)
        for (int l = NDENSE; l < NLVL; ++l) {
            hipLaunchKernelGGL(hash_level_kernel, dim3(nblk), dim3(256), 0, stream,
                               inputs, emb, ws + (size_t)(l - NDENSE) * npts,
                               P.scale[l], P.side[l], P.offset[l], npts);
        }
        // dense levels + interleave + coalesced write
        hipLaunchKernelGGL(finalize_kernel, dim3(nblk), dim3(256), 0, stream,
                           inputs, emb, ws, out, npts, DP);
    } else {
        hipLaunchKernelGGL(grid_encode_mono, dim3(nblk), dim3(256), 0, stream,
                           inputs, emb, out, npts, P);
    }
}

// Round 5
// 466.992 us; speedup vs baseline: 2.3188x; 1.0111x over previous
//
#include <hip/hip_runtime.h>
#include <cstdint>
#include <cmath>

#define NLVL 16
#define NDENSE 5
#define FBLK 1024u
// Levels 0+1 are contiguous from emb[0]: 4920 + 13824 = 18744 entries.
#define TAB_ENTRIES 18744u
// LDS floats: max(staged table 2*18744+pad, transpose 1024*33=33792) -> 37504 floats
#define LDS_FLOATS 37504u
#define LDS_BYTES (LDS_FLOATS * 4u)   // 150016 B <= 160 KiB

typedef float v2f __attribute__((ext_vector_type(2)));
typedef float v4f __attribute__((ext_vector_type(4)));
typedef float v4f8 __attribute__((ext_vector_type(4), aligned(8)));  // 8B-aligned float4

struct Params {
    float    scale[NLVL];
    uint32_t side[NLVL];
    uint32_t offset[NLVL];
    uint32_t hashed[NLVL];
};

struct DenseParams {
    float    scale[NDENSE];
    uint32_t side[NDENSE];
    uint32_t offset[NDENSE];
};

__device__ __forceinline__ uint32_t umin32(uint32_t a, uint32_t b) { return a < b ? a : b; }

// Hashed-level corner pair: adjacent even/odd pair iff c0a even -> one aligned
// dwordx4 serves both; else predicated v2f for corner b.
__device__ __forceinline__ void pair_load(const float* __restrict__ embf,
                                          uint32_t ia, uint32_t ib,
                                          v2f& va, v2f& vb) {
    const v4f q = *(const v4f*)(embf + 2u * (ia & ~1u));
    v2f lo; lo.x = q.x; lo.y = q.y;
    v2f hi; hi.x = q.z; hi.y = q.w;
    va = (ia & 1u) ? hi : lo;
    if ((ia ^ ib) > 1u) {
        vb = *(const v2f*)(embf + 2u * ib);   // predicated: only unpaired lanes
    } else {
        vb = (ib & 1u) ? hi : lo;
    }
}

// Dense-level x-pair from GLOBAL: contiguous (ib = ia+1, or clamped = ia).
__device__ __forceinline__ void dense_pair_load(const float* __restrict__ embf,
                                                uint32_t ia, uint32_t clamped,
                                                v2f& va, v2f& vb) {
    const v4f8 q = *(const v4f8*)(embf + 2u * ia);
    va.x = q.x; va.y = q.y;
    v2f hi; hi.x = q.z; hi.y = q.w;
    vb = clamped ? va : hi;
}

// ---------- Phase kernel: one hashed level (size 2^19, mask 0x7FFFF) ----------
__global__ __launch_bounds__(256) void hash_level_kernel(
    const float* __restrict__ in, const float* __restrict__ embf,
    v2f* __restrict__ wsl, float scale, uint32_t side, uint32_t off, uint32_t npts)
{
    const uint32_t i = blockIdx.x * 256u + threadIdx.x;
    if (i >= npts) return;
    const float x = in[3u * i + 0u];
    const float y = in[3u * i + 1u];
    const float z = in[3u * i + 2u];

    float p0 = x * scale + 0.5f, p1 = y * scale + 0.5f, p2 = z * scale + 0.5f;
    float fl0 = floorf(p0), fl1 = floorf(p1), fl2 = floorf(p2);
    float f0 = p0 - fl0, f1 = p1 - fl1, f2 = p2 - fl2;
    uint32_t g0 = (uint32_t)fl0, g1 = (uint32_t)fl1, g2 = (uint32_t)fl2;

    const uint32_t smax = side - 1u;
    uint32_t c0a = umin32(g0, smax), c0b = umin32(g0 + 1u, smax);
    uint32_t c1a = umin32(g1, smax), c1b = umin32(g1 + 1u, smax);
    uint32_t c2a = umin32(g2, smax), c2b = umin32(g2 + 1u, smax);

    const uint32_t h1a = c1a * 2654435761u, h1b = c1b * 2654435761u;
    const uint32_t h2a = c2a * 805459861u,  h2b = c2b * 805459861u;
    const uint32_t idx0 = ((c0a ^ h1a ^ h2a) & 0x7FFFFu) + off;
    const uint32_t idx1 = ((c0a ^ h1a ^ h2b) & 0x7FFFFu) + off;
    const uint32_t idx2 = ((c0a ^ h1b ^ h2a) & 0x7FFFFu) + off;
    const uint32_t idx3 = ((c0a ^ h1b ^ h2b) & 0x7FFFFu) + off;
    const uint32_t idx4 = ((c0b ^ h1a ^ h2a) & 0x7FFFFu) + off;
    const uint32_t idx5 = ((c0b ^ h1a ^ h2b) & 0x7FFFFu) + off;
    const uint32_t idx6 = ((c0b ^ h1b ^ h2a) & 0x7FFFFu) + off;
    const uint32_t idx7 = ((c0b ^ h1b ^ h2b) & 0x7FFFFu) + off;

    v2f v0, v1, v2, v3, v4, v5, v6, v7;
    pair_load(embf, idx0, idx4, v0, v4);
    pair_load(embf, idx1, idx5, v1, v5);
    pair_load(embf, idx2, idx6, v2, v6);
    pair_load(embf, idx3, idx7, v3, v7);

    const float w0a = 1.0f - f0, w0b = f0;
    const float w1a = 1.0f - f1, w1b = f1;
    const float w2a = 1.0f - f2, w2b = f2;
    v2f r = (w0a * w1a * w2a) * v0 + (w0a * w1a * w2b) * v1
          + (w0a * w1b * w2a) * v2 + (w0a * w1b * w2b) * v3
          + (w0b * w1a * w2a) * v4 + (w0b * w1a * w2b) * v5
          + (w0b * w1b * w2a) * v6 + (w0b * w1b * w2b) * v7;
    __builtin_nontemporal_store(r, wsl + i);
}

// ---------- Finalize: LDS-staged levels 0-1, global levels 2-4, ws 5-15 -> out ----------
__global__ __launch_bounds__(1024, 4) void finalize_kernel(
    const float* __restrict__ in, const float* __restrict__ embf,
    const v2f* __restrict__ ws, float* __restrict__ out,
    uint32_t npts, DenseParams P)
{
    extern __shared__ float lds[];
    const uint32_t t = threadIdx.x;
    const uint32_t i = blockIdx.x * FBLK + t;

    // Phase A: stage emb[0 .. TAB_ENTRIES) (levels 0+1, contiguous) into LDS.
    {
        const v4f* src4 = (const v4f*)embf;
        v4f* dst4 = (v4f*)lds;
        #pragma unroll
        for (uint32_t j = 0; j < 10; ++j) {
            const uint32_t k = j * FBLK + t;
            if (k < LDS_FLOATS / 4u) dst4[k] = src4[k];
        }
    }

    const float x = in[3u * i + 0u];
    const float y = in[3u * i + 1u];
    const float z = in[3u * i + 2u];

    __syncthreads();

    float res[32];   // fully static-indexed (unrolled) -> registers

    // dense levels; 0-1 from LDS, 2-4 from global (L2-resident)
    #pragma unroll
    for (int l = 0; l < NDENSE; ++l) {
        const float scale = P.scale[l];
        const uint32_t side = P.side[l];
        const uint32_t off  = P.offset[l];

        float p0 = x * scale + 0.5f, p1 = y * scale + 0.5f, p2 = z * scale + 0.5f;
        float fl0 = floorf(p0), fl1 = floorf(p1), fl2 = floorf(p2);
        float f0 = p0 - fl0, f1 = p1 - fl1, f2 = p2 - fl2;
        uint32_t g0 = (uint32_t)fl0, g1 = (uint32_t)fl1, g2 = (uint32_t)fl2;

        const uint32_t smax = side - 1u;
        uint32_t c0a = umin32(g0, smax);
        const uint32_t clamped = (c0a == smax) ? 1u : 0u;   // c0b == c0a
        uint32_t c1a = umin32(g1, smax), c1b = umin32(g1 + 1u, smax);
        uint32_t c2a = umin32(g2, smax), c2b = umin32(g2 + 1u, smax);

        const uint32_t s2 = side * side;
        const uint32_t ia0 = c0a + c1a * side + c2a * s2 + off;
        const uint32_t ia1 = c0a + c1a * side + c2b * s2 + off;
        const uint32_t ia2 = c0a + c1b * side + c2a * s2 + off;
        const uint32_t ia3 = c0a + c1b * side + c2b * s2 + off;

        v2f v0, v1, v2, v3, v4, v5, v6, v7;
        if (l < 2) {
            // LDS path: two ds_read_b64 per x-pair; idx+1 read stays inside the
            // LDS allocation even at the clamped edge (LDS_FLOATS padded).
            v0 = *(const v2f*)(lds + 2u * ia0);
            v4 = clamped ? v0 : *(const v2f*)(lds + 2u * ia0 + 2u);
            v1 = *(const v2f*)(lds + 2u * ia1);
            v5 = clamped ? v1 : *(const v2f*)(lds + 2u * ia1 + 2u);
            v2 = *(const v2f*)(lds + 2u * ia2);
            v6 = clamped ? v2 : *(const v2f*)(lds + 2u * ia2 + 2u);
            v3 = *(const v2f*)(lds + 2u * ia3);
            v7 = clamped ? v3 : *(const v2f*)(lds + 2u * ia3 + 2u);
        } else {
            dense_pair_load(embf, ia0, clamped, v0, v4);
            dense_pair_load(embf, ia1, clamped, v1, v5);
            dense_pair_load(embf, ia2, clamped, v2, v6);
            dense_pair_load(embf, ia3, clamped, v3, v7);
        }

        const float w0a = 1.0f - f0, w0b = f0;
        const float w1a = 1.0f - f1, w1b = f1;
        const float w2a = 1.0f - f2, w2b = f2;
        v2f r = (w0a * w1a * w2a) * v0 + (w0a * w1a * w2b) * v1
              + (w0a * w1b * w2a) * v2 + (w0a * w1b * w2b) * v3
              + (w0b * w1a * w2a) * v4 + (w0b * w1a * w2b) * v5
              + (w0b * w1b * w2a) * v6 + (w0b * w1b * w2b) * v7;
        res[2 * l]     = r.x;
        res[2 * l + 1] = r.y;
    }

    // hashed levels 5..15 from workspace (coalesced)
    #pragma unroll
    for (int l = NDENSE; l < NLVL; ++l) {
        v2f r = __builtin_nontemporal_load(ws + (size_t)(l - NDENSE) * npts + i);
        res[2 * l]     = r.x;
        res[2 * l + 1] = r.y;
    }

    // Phase B: reuse LDS as [1024][33] transpose buffer
    __syncthreads();
    {
        float* row = lds + t * 33u;
        #pragma unroll
        for (int k = 0; k < 32; ++k) row[k] = res[k];   // stride 33: conflict-free
    }
    __syncthreads();

    // coalesced output: block's 128 KB chunk written contiguously
    float* obase = out + (size_t)blockIdx.x * FBLK * 32u;
    #pragma unroll
    for (uint32_t k = 0; k < 8; ++k) {
        const uint32_t f = k * 4096u + t * 4u;          // float idx in chunk
        const uint32_t p = f >> 5, c = f & 31u;
        const float* src = lds + p * 33u + c;
        v4f q; q.x = src[0]; q.y = src[1]; q.z = src[2]; q.w = src[3];
        __builtin_nontemporal_store(q, (v4f*)(obase + f));
    }
}

// ---------- Fallback: monolithic kernel (used if ws too small / odd sizes) ----------
__global__ __launch_bounds__(256) void grid_encode_mono(
    const float* __restrict__ in, const float* __restrict__ emb,
    float* __restrict__ out, uint32_t npts, Params P)
{
    const uint32_t i = blockIdx.x * 256u + threadIdx.x;
    if (i >= npts) return;
    const float x = in[3u * i + 0u], y = in[3u * i + 1u], z = in[3u * i + 2u];
    const v2f* e2 = (const v2f*)emb;
    float* outp = out + (size_t)i * 32u;

    #pragma unroll 1
    for (int l = 0; l < NLVL; ++l) {
        const float scale = P.scale[l];
        const uint32_t side = P.side[l], off = P.offset[l], hashed = P.hashed[l];
        float p0 = x * scale + 0.5f, p1 = y * scale + 0.5f, p2 = z * scale + 0.5f;
        float fl0 = floorf(p0), fl1 = floorf(p1), fl2 = floorf(p2);
        float f0 = p0 - fl0, f1 = p1 - fl1, f2 = p2 - fl2;
        uint32_t g0 = (uint32_t)fl0, g1 = (uint32_t)fl1, g2 = (uint32_t)fl2;
        const uint32_t smax = side - 1u;
        uint32_t c0a = umin32(g0, smax), c0b = umin32(g0 + 1u, smax);
        uint32_t c1a = umin32(g1, smax), c1b = umin32(g1 + 1u, smax);
        uint32_t c2a = umin32(g2, smax), c2b = umin32(g2 + 1u, smax);
        uint32_t idx0, idx1, idx2, idx3, idx4, idx5, idx6, idx7;
        if (hashed) {
            const uint32_t h1a = c1a * 2654435761u, h1b = c1b * 2654435761u;
            const uint32_t h2a = c2a * 805459861u,  h2b = c2b * 805459861u;
            idx0 = ((c0a ^ h1a ^ h2a) & 0x7FFFFu) + off;
            idx1 = ((c0a ^ h1a ^ h2b) & 0x7FFFFu) + off;
            idx2 = ((c0a ^ h1b ^ h2a) & 0x7FFFFu) + off;
            idx3 = ((c0a ^ h1b ^ h2b) & 0x7FFFFu) + off;
            idx4 = ((c0b ^ h1a ^ h2a) & 0x7FFFFu) + off;
            idx5 = ((c0b ^ h1a ^ h2b) & 0x7FFFFu) + off;
            idx6 = ((c0b ^ h1b ^ h2a) & 0x7FFFFu) + off;
            idx7 = ((c0b ^ h1b ^ h2b) & 0x7FFFFu) + off;
        } else {
            const uint32_t s2 = side * side;
            const uint32_t b1a = c1a * side, b1b = c1b * side;
            const uint32_t b2a = c2a * s2,   b2b = c2b * s2;
            idx0 = (c0a + b1a + b2a) + off; idx1 = (c0a + b1a + b2b) + off;
            idx2 = (c0a + b1b + b2a) + off; idx3 = (c0a + b1b + b2b) + off;
            idx4 = (c0b + b1a + b2a) + off; idx5 = (c0b + b1a + b2b) + off;
            idx6 = (c0b + b1b + b2a) + off; idx7 = (c0b + b1b + b2b) + off;
        }
        const v2f v0 = e2[idx0], v1 = e2[idx1], v2 = e2[idx2], v3 = e2[idx3];
        const v2f v4 = e2[idx4], v5 = e2[idx5], v6 = e2[idx6], v7 = e2[idx7];
        const float w0a = 1.0f - f0, w0b = f0;
        const float w1a = 1.0f - f1, w1b = f1;
        const float w2a = 1.0f - f2, w2b = f2;
        v2f r = (w0a*w1a*w2a) * v0 + (w0a*w1a*w2b) * v1 + (w0a*w1b*w2a) * v2 + (w0a*w1b*w2b) * v3
              + (w0b*w1a*w2a) * v4 + (w0b*w1a*w2b) * v5 + (w0b*w1b*w2a) * v6 + (w0b*w1b*w2b) * v7;
        *(v2f*)(outp + 2 * l) = r;
    }
}

extern "C" void kernel_launch(void* const* d_in, const int* in_sizes, int n_in,
                              void* d_out, int out_size, void* d_ws, size_t ws_size,
                              hipStream_t stream) {
    const float* inputs = (const float*)d_in[0];
    const float* emb    = (const float*)d_in[1];
    float* out          = (float*)d_out;

    // Mirror GridEncoder.__init__ level config in double precision (matches numpy).
    Params P;
    DenseParams DP;
    const double PLS = exp2(log2(2048.0 / 16.0) / 15.0);
    uint64_t off = 0;
    for (int l = 0; l < NLVL; ++l) {
        const double s = 16.0 * pow(PLS, (double)l);
        const uint32_t side = (uint32_t)ceil(s) + 1u;
        const uint64_t s3 = (uint64_t)side * side * side;
        uint64_t params = s3 < (1ull << 19) ? s3 : (1ull << 19);
        params = (params + 7ull) / 8ull * 8ull;
        P.scale[l]  = (float)(s - 1.0);
        P.side[l]   = side;
        P.offset[l] = (uint32_t)off;
        P.hashed[l] = (s3 > params) ? 1u : 0u;
        if (l < NDENSE) { DP.scale[l] = P.scale[l]; DP.side[l] = P.side[l]; DP.offset[l] = P.offset[l]; }
        off += params;
    }

    const uint32_t npts = (uint32_t)(in_sizes[0] / 3);
    const uint32_t nblk = (npts + 255u) / 256u;
    const size_t ws_needed = (size_t)(NLVL - NDENSE) * npts * sizeof(v2f);

    if (ws_size >= ws_needed && (npts % FBLK) == 0u) {
        v2f* ws = (v2f*)d_ws;
        // hashed levels 5..15, one kernel each (temporal phasing for L2 residency)
        for (int l = NDENSE; l < NLVL; ++l) {
            hipLaunchKernelGGL(hash_level_kernel, dim3(nblk), dim3(256), 0, stream,
                               inputs, emb, ws + (size_t)(l - NDENSE) * npts,
                               P.scale[l], P.side[l], P.offset[l], npts);
        }
        // allow >64 KiB dynamic LDS (host-side attribute set; graph-capture-safe)
        static bool attr_set = [] {
            hipFuncSetAttribute(reinterpret_cast<const void*>(finalize_kernel),
                                hipFuncAttributeMaxDynamicSharedMemorySize, LDS_BYTES);
            return true;
        }();
        (void)attr_set;
        hipLaunchKernelGGL(finalize_kernel, dim3(npts / FBLK), dim3(FBLK), LDS_BYTES, stream,
                           inputs, emb, ws, out, npts, DP);
    } else {
        hipLaunchKernelGGL(grid_encode_mono, dim3(nblk), dim3(256), 0, stream,
                           inputs, emb, out, npts, P);
    }
}